// Round 6
// baseline (495.163 us; speedup 1.0000x reference)
//
#include <hip/hip_runtime.h>

#define NEG_SLOPE 0.2f

__device__ __forceinline__ float leaky(float x) { return x > 0.f ? x : NEG_SLOPE * x; }

__device__ __forceinline__ void unpack2(unsigned u, float& lo, float& hi) {
    union { unsigned u; float f; } a, b;
    a.u = u << 16; b.u = u & 0xffff0000u;
    lo = a.f; hi = b.f;
}

__device__ __forceinline__ unsigned short f2bf(float f) {
    unsigned u = __float_as_uint(f);
    u += 0x7fffu + ((u >> 16) & 1u);
    return (unsigned short)(u >> 16);
}

// ---------------- CSR build (dst -> incoming srcs), shared by both layers ----------------
__global__ void k_count(const int* __restrict__ dst, int E, int* __restrict__ cnt) {
    int i = blockIdx.x * blockDim.x + threadIdx.x;
    if (i < E) atomicAdd(&cnt[dst[i]], 1);
}

__global__ __launch_bounds__(256) void k_scanA(const int* __restrict__ cnt, int* __restrict__ rowptr,
                                               int* __restrict__ bsum, int n) {
    int b = blockIdx.x, t = threadIdx.x;
    int lane = t & 63, w = t >> 6;
    int i0 = b * 1024 + t * 4;
    int v0 = (i0 + 0 < n) ? cnt[i0 + 0] : 0;
    int v1 = (i0 + 1 < n) ? cnt[i0 + 1] : 0;
    int v2 = (i0 + 2 < n) ? cnt[i0 + 2] : 0;
    int v3 = (i0 + 3 < n) ? cnt[i0 + 3] : 0;
    int r0 = v0, r1 = r0 + v1, r2 = r1 + v2, r3 = r2 + v3;
    int s = r3;
    int q = s;
    #pragma unroll
    for (int off = 1; off < 64; off <<= 1) {
        int tval = __shfl_up(q, off);
        if (lane >= off) q += tval;
    }
    __shared__ int wsum[4];
    if (lane == 63) wsum[w] = q;
    __syncthreads();
    int woff = 0;
    #pragma unroll
    for (int k = 0; k < 4; k++) if (k < w) woff += wsum[k];
    int excl = woff + q - s;
    if (i0 + 0 < n) rowptr[1 + i0 + 0] = excl + r0;
    if (i0 + 1 < n) rowptr[1 + i0 + 1] = excl + r1;
    if (i0 + 2 < n) rowptr[1 + i0 + 2] = excl + r2;
    if (i0 + 3 < n) rowptr[1 + i0 + 3] = excl + r3;
    if (t == 255) bsum[b] = woff + q;
}

__global__ void k_scanB(const int* __restrict__ bsum, int* __restrict__ bscan, int nb) {
    int lane = threadIdx.x & 63;
    int v = (lane < nb) ? bsum[lane] : 0;
    #pragma unroll
    for (int off = 1; off < 64; off <<= 1) {
        int t = __shfl_up(v, off);
        if (lane >= off) v += t;
    }
    if (lane < nb) bscan[lane] = v;
}

__global__ __launch_bounds__(256) void k_scanC(int* __restrict__ rowptr, const int* __restrict__ bscan, int n) {
    int b = blockIdx.x, t = threadIdx.x;
    int i0 = b * 1024 + t * 4;
    if (b == 0) {
        if (t == 0) rowptr[0] = 0;
        return;
    }
    int add = bscan[b - 1];
    #pragma unroll
    for (int j = 0; j < 4; j++)
        if (i0 + j < n) rowptr[1 + i0 + j] += add;
}

__global__ void k_copy(const int* __restrict__ src, int* __restrict__ dst, int n) {
    int i = blockIdx.x * blockDim.x + threadIdx.x;
    if (i < n) dst[i] = src[i];
}

__global__ void k_scatter(const int* __restrict__ srcn, const int* __restrict__ dstn, int E,
                          int* __restrict__ wptr, int* __restrict__ col) {
    int i = blockIdx.x * blockDim.x + threadIdx.x;
    if (i < E) {
        int d = dstn[i];
        int pos = atomicAdd(&wptr[d], 1);
        col[pos] = srcn[i];
    }
}

// ---------------- tiled fp32 GEMM with optional bf16 out + fused alpha ----------------
template <int BMT, bool WF32, bool WBF16, bool FALPHA>
__global__ __launch_bounds__(256) void k_gemm(const float* __restrict__ A, const float* __restrict__ B,
                                              float* __restrict__ C, unsigned short* __restrict__ Cb,
                                              const float* __restrict__ a_s, const float* __restrict__ a_d,
                                              float* __restrict__ asrc, float* __restrict__ adst,
                                              int M, int N, int K) {
    constexpr int RT = BMT / 16;
    constexpr int APASS = BMT / 32;
    __shared__ float As[32][BMT + 4];
    __shared__ float Bs[32][68];
    int row0 = blockIdx.x * BMT, col0 = blockIdx.y * 64;
    int tid = threadIdx.x;
    int tx = tid & 15, ty = tid >> 4;
    float acc[RT][4] = {};
    for (int kk = 0; kk < K; kk += 32) {
        int ar = tid >> 3;
        int ac = (tid & 7) * 4;
        #pragma unroll
        for (int p = 0; p < APASS; p++) {
            int r = ar + p * 32;
            int gr = row0 + r;
            float4 v = make_float4(0.f, 0.f, 0.f, 0.f);
            if (gr < M) v = *reinterpret_cast<const float4*>(&A[(size_t)gr * K + kk + ac]);
            As[ac + 0][r] = v.x; As[ac + 1][r] = v.y;
            As[ac + 2][r] = v.z; As[ac + 3][r] = v.w;
        }
        int br = tid >> 4;
        int bc = (tid & 15) * 4;
        #pragma unroll
        for (int p = 0; p < 2; p++) {
            int r = br + p * 16;
            float4 v = *reinterpret_cast<const float4*>(&B[(size_t)(kk + r) * N + col0 + bc]);
            *reinterpret_cast<float4*>(&Bs[r][bc]) = v;
        }
        __syncthreads();
        #pragma unroll
        for (int k = 0; k < 32; k++) {
            float a[RT];
            #pragma unroll
            for (int i = 0; i < RT; i += 4) {
                float4 av = *reinterpret_cast<const float4*>(&As[k][ty * RT + i]);
                a[i + 0] = av.x; a[i + 1] = av.y; a[i + 2] = av.z; a[i + 3] = av.w;
            }
            float4 bv = *reinterpret_cast<const float4*>(&Bs[k][tx * 4]);
            float b[4] = {bv.x, bv.y, bv.z, bv.w};
            #pragma unroll
            for (int i = 0; i < RT; i++)
                #pragma unroll
                for (int j = 0; j < 4; j++) acc[i][j] = fmaf(a[i], b[j], acc[i][j]);
        }
        __syncthreads();
    }
    float4 as4, ad4;
    if (FALPHA) {
        as4 = *reinterpret_cast<const float4*>(&a_s[col0 + tx * 4]);
        ad4 = *reinterpret_cast<const float4*>(&a_d[col0 + tx * 4]);
    }
    int HV = N >> 6, hd = col0 >> 6;
    #pragma unroll
    for (int i = 0; i < RT; i++) {
        int gr = row0 + ty * RT + i;
        if (gr < M) {
            if (WF32) {
                float4 v = make_float4(acc[i][0], acc[i][1], acc[i][2], acc[i][3]);
                *reinterpret_cast<float4*>(&C[(size_t)gr * N + col0 + tx * 4]) = v;
            }
            if (WBF16) {
                ushort4 u;
                u.x = f2bf(acc[i][0]); u.y = f2bf(acc[i][1]);
                u.z = f2bf(acc[i][2]); u.w = f2bf(acc[i][3]);
                *reinterpret_cast<ushort4*>(&Cb[(size_t)gr * N + col0 + tx * 4]) = u;
            }
            if (FALPHA) {
                float ps = acc[i][0] * as4.x + acc[i][1] * as4.y + acc[i][2] * as4.z + acc[i][3] * as4.w;
                float pd = acc[i][0] * ad4.x + acc[i][1] * ad4.y + acc[i][2] * ad4.z + acc[i][3] * ad4.w;
                #pragma unroll
                for (int off = 1; off <= 8; off <<= 1) { ps += __shfl_xor(ps, off); pd += __shfl_xor(pd, off); }
                if (tx == 0) { asrc[(size_t)gr * HV + hd] = ps; adst[(size_t)gr * HV + hd] = pd; }
            }
        }
    }
}

// ---------------- attention aggregation, layer 1 (bf16 gather, no max pass) ----------------
// block = node; wave = head; lane: q = l&7 (8 channels via bf16x8), rep = l>>3 (8 edge reps).
__global__ __launch_bounds__(256) void k_agg1(const unsigned short* __restrict__ hb,
                                              const float* __restrict__ asrc, const float* __restrict__ adst,
                                              const int* __restrict__ rowptr, const int* __restrict__ col,
                                              const float* __restrict__ bias, float* __restrict__ out, int n) {
    int node = blockIdx.x;
    int t = threadIdx.x, hd = t >> 6, l = t & 63;
    int rep = l >> 3, q = l & 7;
    int base = rowptr[node], deg = rowptr[node + 1] - base;
    float adst_n = adst[node * 4 + hd];
    float p_self = __expf(leaky(asrc[node * 4 + hd] + adst_n));
    float acc[8] = {};
    float dsum = 0.f;
    if (rep == 0) {
        uint4 u = *reinterpret_cast<const uint4*>(&hb[(size_t)node * 256 + hd * 64 + q * 8]);
        float f[8];
        unpack2(u.x, f[0], f[1]); unpack2(u.y, f[2], f[3]);
        unpack2(u.z, f[4], f[5]); unpack2(u.w, f[6], f[7]);
        #pragma unroll
        for (int j = 0; j < 8; j++) acc[j] = p_self * f[j];
        dsum = p_self;
    }

    for (int c0 = 0; c0 < deg; c0 += 16) {
        int ia = c0 + rep, ib = ia + 8;
        bool va = ia < deg, vb = ib < deg;
        int sa = 0, sb = 0;
        if (va) sa = col[base + ia];
        if (vb) sb = col[base + ib];
        uint4 ua = make_uint4(0, 0, 0, 0), ub = make_uint4(0, 0, 0, 0);
        if (va) ua = *reinterpret_cast<const uint4*>(&hb[(size_t)sa * 256 + hd * 64 + q * 8]);
        if (vb) ub = *reinterpret_cast<const uint4*>(&hb[(size_t)sb * 256 + hd * 64 + q * 8]);
        float pa = 0.f, pb = 0.f;
        if (va) pa = __expf(leaky(asrc[sa * 4 + hd] + adst_n));
        if (vb) pb = __expf(leaky(asrc[sb * 4 + hd] + adst_n));
        float f[8];
        unpack2(ua.x, f[0], f[1]); unpack2(ua.y, f[2], f[3]);
        unpack2(ua.z, f[4], f[5]); unpack2(ua.w, f[6], f[7]);
        #pragma unroll
        for (int j = 0; j < 8; j++) acc[j] = fmaf(pa, f[j], acc[j]);
        unpack2(ub.x, f[0], f[1]); unpack2(ub.y, f[2], f[3]);
        unpack2(ub.z, f[4], f[5]); unpack2(ub.w, f[6], f[7]);
        #pragma unroll
        for (int j = 0; j < 8; j++) acc[j] = fmaf(pb, f[j], acc[j]);
        dsum += pa + pb;  // redundant across q; reduced over rep bits below
    }
    // butterfly over rep bits (3,4,5): acc and dsum together
    #pragma unroll
    for (int off = 8; off <= 32; off <<= 1) {
        #pragma unroll
        for (int j = 0; j < 8; j++) acc[j] += __shfl_xor(acc[j], off);
        dsum += __shfl_xor(dsum, off);
    }
    if (rep == 0) {
        float inv = 1.f / (dsum + 1e-16f);
        float r[8];
        #pragma unroll
        for (int j = 0; j < 8; j++) r[j] = fmaxf(acc[j] * inv + bias[hd * 64 + q * 8 + j], 0.f);
        float4 v0 = make_float4(r[0], r[1], r[2], r[3]);
        float4 v1 = make_float4(r[4], r[5], r[6], r[7]);
        *reinterpret_cast<float4*>(&out[(size_t)node * 256 + hd * 64 + q * 8]) = v0;
        *reinterpret_cast<float4*>(&out[(size_t)node * 256 + hd * 64 + q * 8 + 4]) = v1;
    }
}

// ---------------- attention aggregation, layer 2 (bf16 gather) + fused FC ----------------
// wave = node (4 nodes/block); lane: q = l&7 (8 channels), rep = l>>3 (8 edge reps).
__global__ __launch_bounds__(256) void k_agg2fc(const unsigned short* __restrict__ hb,
                                                const float* __restrict__ asrc, const float* __restrict__ adst,
                                                const int* __restrict__ rowptr, const int* __restrict__ col,
                                                const float* __restrict__ bias, const float* __restrict__ Wfc,
                                                const float* __restrict__ bfc, float* __restrict__ out, int n) {
    int node = blockIdx.x * 4 + (threadIdx.x >> 6);
    int l = threadIdx.x & 63;
    if (node >= n) return;
    int rep = l >> 3, q = l & 7;
    int base = rowptr[node], deg = rowptr[node + 1] - base;
    float adst_n = adst[node];
    float p_self = __expf(leaky(asrc[node] + adst_n));
    float acc[8] = {};
    float dsum = 0.f;
    if (rep == 0) {
        uint4 u = *reinterpret_cast<const uint4*>(&hb[(size_t)node * 64 + q * 8]);
        float f[8];
        unpack2(u.x, f[0], f[1]); unpack2(u.y, f[2], f[3]);
        unpack2(u.z, f[4], f[5]); unpack2(u.w, f[6], f[7]);
        #pragma unroll
        for (int j = 0; j < 8; j++) acc[j] = p_self * f[j];
        dsum = p_self;
    }

    for (int c0 = 0; c0 < deg; c0 += 16) {
        int ia = c0 + rep, ib = ia + 8;
        bool va = ia < deg, vb = ib < deg;
        int sa = 0, sb = 0;
        if (va) sa = col[base + ia];
        if (vb) sb = col[base + ib];
        uint4 ua = make_uint4(0, 0, 0, 0), ub = make_uint4(0, 0, 0, 0);
        if (va) ua = *reinterpret_cast<const uint4*>(&hb[(size_t)sa * 64 + q * 8]);
        if (vb) ub = *reinterpret_cast<const uint4*>(&hb[(size_t)sb * 64 + q * 8]);
        float pa = 0.f, pb = 0.f;
        if (va) pa = __expf(leaky(asrc[sa] + adst_n));
        if (vb) pb = __expf(leaky(asrc[sb] + adst_n));
        float f[8];
        unpack2(ua.x, f[0], f[1]); unpack2(ua.y, f[2], f[3]);
        unpack2(ua.z, f[4], f[5]); unpack2(ua.w, f[6], f[7]);
        #pragma unroll
        for (int j = 0; j < 8; j++) acc[j] = fmaf(pa, f[j], acc[j]);
        unpack2(ub.x, f[0], f[1]); unpack2(ub.y, f[2], f[3]);
        unpack2(ub.z, f[4], f[5]); unpack2(ub.w, f[6], f[7]);
        #pragma unroll
        for (int j = 0; j < 8; j++) acc[j] = fmaf(pb, f[j], acc[j]);
        dsum += pa + pb;
    }
    #pragma unroll
    for (int off = 8; off <= 32; off <<= 1) {
        #pragma unroll
        for (int j = 0; j < 8; j++) acc[j] += __shfl_xor(acc[j], off);
        dsum += __shfl_xor(dsum, off);
    }
    float inv = 1.f / (dsum + 1e-16f);
    float r[8];
    #pragma unroll
    for (int j = 0; j < 8; j++) r[j] = fmaxf(acc[j] * inv + bias[q * 8 + j], 0.f);
    // fused FC over the 8 q-groups (lane bits 0..2)
    #pragma unroll
    for (int a = 0; a < 5; a++) {
        float part = 0.f;
        #pragma unroll
        for (int j = 0; j < 8; j++) part = fmaf(r[j], Wfc[(q * 8 + j) * 5 + a], part);
        #pragma unroll
        for (int off = 1; off <= 4; off <<= 1) part += __shfl_xor(part, off);
        if (l == 0) out[(size_t)node * 5 + a] = part + bfc[a];
    }
}

extern "C" void kernel_launch(void* const* d_in, const int* in_sizes, int n_in,
                              void* d_out, int out_size, void* d_ws, size_t ws_size,
                              hipStream_t stream) {
    const float* x   = (const float*)d_in[0];
    const int*   ei  = (const int*)d_in[1];
    const float* W1  = (const float*)d_in[2];
    const float* a1s = (const float*)d_in[3];
    const float* a1d = (const float*)d_in[4];
    const float* b1  = (const float*)d_in[5];
    const float* W2  = (const float*)d_in[6];
    const float* a2s = (const float*)d_in[7];
    const float* a2d = (const float*)d_in[8];
    const float* b2  = (const float*)d_in[9];
    const float* Wfc = (const float*)d_in[10];
    const float* bfc = (const float*)d_in[11];
    float* out = (float*)d_out;

    int n = in_sizes[0] / 128;
    int E = in_sizes[1] / 2;
    const int* srcn = ei;
    const int* dstn = ei + E;

    char* ws = (char*)d_ws;
    size_t off = 0;
    auto alloc = [&](size_t bytes) -> void* {
        void* p = ws + off;
        off += (bytes + 255) & ~(size_t)255;
        return p;
    };
    unsigned short* h1b = (unsigned short*)alloc((size_t)n * 256 * 2);
    float* out1   = (float*)alloc((size_t)n * 256 * 4);
    unsigned short* h2b = (unsigned short*)alloc((size_t)n * 64 * 2);
    float* asrc1  = (float*)alloc((size_t)n * 4 * 4);
    float* adst1  = (float*)alloc((size_t)n * 4 * 4);
    int*   rowptr = (int*)alloc((size_t)(n + 1) * 4);
    int*   wptr   = (int*)alloc((size_t)n * 4);
    int*   col    = (int*)alloc((size_t)E * 4);
    int*   bsum   = (int*)alloc(64 * 4);
    int*   bscan  = (int*)alloc(64 * 4);
    float* asrc2 = asrc1;  // layer-1 versions dead before gemm2 writes these
    float* adst2 = adst1;

    int nb = (n + 1023) / 1024;

    // ---- CSR build (once; graph shared by both layers) ----
    hipMemsetAsync(wptr, 0, (size_t)n * 4, stream);
    k_count<<<(E + 255) / 256, 256, 0, stream>>>(dstn, E, wptr);
    k_scanA<<<nb, 256, 0, stream>>>(wptr, rowptr, bsum, n);
    k_scanB<<<1, 64, 0, stream>>>(bsum, bscan, nb);
    k_scanC<<<nb, 256, 0, stream>>>(rowptr, bscan, n);
    k_copy<<<(n + 255) / 256, 256, 0, stream>>>(rowptr, wptr, n);
    k_scatter<<<(E + 255) / 256, 256, 0, stream>>>(srcn, dstn, E, wptr, col);

    // ---- layer 1: GEMM (bf16 out + fused alpha), then aggregation ----
    k_gemm<128, false, true, true><<<dim3((n + 127) / 128, 4), 256, 0, stream>>>(
        x, W1, nullptr, h1b, a1s, a1d, asrc1, adst1, n, 256, 128);
    k_agg1<<<n, 256, 0, stream>>>(h1b, asrc1, adst1, rowptr, col, b1, out1, n);
    // ---- layer 2: GEMM (bf16 out + fused alpha), aggregation + FC fused ----
    k_gemm<64, false, true, true><<<dim3((n + 63) / 64, 1), 256, 0, stream>>>(
        out1, W2, nullptr, h2b, a2s, a2d, asrc2, adst2, n, 64, 256);
    k_agg2fc<<<(n + 3) / 4, 256, 0, stream>>>(h2b, asrc2, adst2, rowptr, col, b2, Wfc, bfc, out, n);
}

// Round 11
// 473.509 us; speedup vs baseline: 1.0457x; 1.0457x over previous
//
#include <hip/hip_runtime.h>

#define NEG_SLOPE 0.2f
#define ELLW 32

__device__ __forceinline__ float leaky(float x) { return x > 0.f ? x : NEG_SLOPE * x; }

__device__ __forceinline__ void unpack2(unsigned u, float& lo, float& hi) {
    union { unsigned u; float f; } a, b;
    a.u = u << 16; b.u = u & 0xffff0000u;
    lo = a.f; hi = b.f;
}

__device__ __forceinline__ unsigned short f2bf(float f) {
    unsigned u = __float_as_uint(f);
    u += 0x7fffu + ((u >> 16) & 1u);
    return (unsigned short)(u >> 16);
}

// ---------------- CSR + ELL build (dst -> incoming srcs), shared by both layers ----------------
__global__ void k_count(const int* __restrict__ dst, int E, int* __restrict__ cnt) {
    int i = blockIdx.x * blockDim.x + threadIdx.x;
    if (i < E) atomicAdd(&cnt[dst[i]], 1);
}

__global__ __launch_bounds__(256) void k_scanA(const int* __restrict__ cnt, int* __restrict__ rowptr,
                                               int* __restrict__ bsum, int n) {
    int b = blockIdx.x, t = threadIdx.x;
    int lane = t & 63, w = t >> 6;
    int i0 = b * 1024 + t * 4;
    int v0 = (i0 + 0 < n) ? cnt[i0 + 0] : 0;
    int v1 = (i0 + 1 < n) ? cnt[i0 + 1] : 0;
    int v2 = (i0 + 2 < n) ? cnt[i0 + 2] : 0;
    int v3 = (i0 + 3 < n) ? cnt[i0 + 3] : 0;
    int r0 = v0, r1 = r0 + v1, r2 = r1 + v2, r3 = r2 + v3;
    int s = r3;
    int q = s;
    #pragma unroll
    for (int off = 1; off < 64; off <<= 1) {
        int tval = __shfl_up(q, off);
        if (lane >= off) q += tval;
    }
    __shared__ int wsum[4];
    if (lane == 63) wsum[w] = q;
    __syncthreads();
    int woff = 0;
    #pragma unroll
    for (int k = 0; k < 4; k++) if (k < w) woff += wsum[k];
    int excl = woff + q - s;
    if (i0 + 0 < n) rowptr[1 + i0 + 0] = excl + r0;
    if (i0 + 1 < n) rowptr[1 + i0 + 1] = excl + r1;
    if (i0 + 2 < n) rowptr[1 + i0 + 2] = excl + r2;
    if (i0 + 3 < n) rowptr[1 + i0 + 3] = excl + r3;
    if (t == 255) bsum[b] = woff + q;
}

__global__ void k_scanB(const int* __restrict__ bsum, int* __restrict__ bscan, int nb) {
    int lane = threadIdx.x & 63;
    int v = (lane < nb) ? bsum[lane] : 0;
    #pragma unroll
    for (int off = 1; off < 64; off <<= 1) {
        int t = __shfl_up(v, off);
        if (lane >= off) v += t;
    }
    if (lane < nb) bscan[lane] = v;
}

__global__ __launch_bounds__(256) void k_scanC(int* __restrict__ rowptr, const int* __restrict__ bscan, int n) {
    int b = blockIdx.x, t = threadIdx.x;
    int i0 = b * 1024 + t * 4;
    if (b == 0) {
        if (t == 0) rowptr[0] = 0;
        return;
    }
    int add = bscan[b - 1];
    #pragma unroll
    for (int j = 0; j < 4; j++)
        if (i0 + j < n) rowptr[1 + i0 + j] += add;
}

__global__ void k_copy(const int* __restrict__ src, int* __restrict__ dst, int n) {
    int i = blockIdx.x * blockDim.x + threadIdx.x;
    if (i < n) dst[i] = src[i];
}

// scatter into CSR col[] AND fixed-width ELL (first ELLW edges per node; rest via CSR tail)
__global__ void k_scatter(const int* __restrict__ srcn, const int* __restrict__ dstn, int E,
                          const int* __restrict__ rowptr, int* __restrict__ wptr,
                          int* __restrict__ col, int* __restrict__ ell) {
    int i = blockIdx.x * blockDim.x + threadIdx.x;
    if (i < E) {
        int d = dstn[i];
        int s = srcn[i];
        int pos = atomicAdd(&wptr[d], 1);          // global CSR position
        col[pos] = s;
        int slot = pos - rowptr[d];
        if (slot < ELLW) ell[(size_t)d * ELLW + slot] = s;
    }
}

// ---------------- tiled fp32 GEMM with optional bf16 out + fused alpha ----------------
template <int BMT, bool WF32, bool WBF16, bool FALPHA>
__global__ __launch_bounds__(256) void k_gemm(const float* __restrict__ A, const float* __restrict__ B,
                                              float* __restrict__ C, unsigned short* __restrict__ Cb,
                                              const float* __restrict__ a_s, const float* __restrict__ a_d,
                                              float* __restrict__ asrc, float* __restrict__ adst,
                                              int M, int N, int K) {
    constexpr int RT = BMT / 16;
    constexpr int APASS = BMT / 32;
    __shared__ float As[32][BMT + 4];
    __shared__ float Bs[32][68];
    int row0 = blockIdx.x * BMT, col0 = blockIdx.y * 64;
    int tid = threadIdx.x;
    int tx = tid & 15, ty = tid >> 4;
    float acc[RT][4] = {};
    for (int kk = 0; kk < K; kk += 32) {
        int ar = tid >> 3;
        int ac = (tid & 7) * 4;
        #pragma unroll
        for (int p = 0; p < APASS; p++) {
            int r = ar + p * 32;
            int gr = row0 + r;
            float4 v = make_float4(0.f, 0.f, 0.f, 0.f);
            if (gr < M) v = *reinterpret_cast<const float4*>(&A[(size_t)gr * K + kk + ac]);
            As[ac + 0][r] = v.x; As[ac + 1][r] = v.y;
            As[ac + 2][r] = v.z; As[ac + 3][r] = v.w;
        }
        int br = tid >> 4;
        int bc = (tid & 15) * 4;
        #pragma unroll
        for (int p = 0; p < 2; p++) {
            int r = br + p * 16;
            float4 v = *reinterpret_cast<const float4*>(&B[(size_t)(kk + r) * N + col0 + bc]);
            *reinterpret_cast<float4*>(&Bs[r][bc]) = v;
        }
        __syncthreads();
        #pragma unroll
        for (int k = 0; k < 32; k++) {
            float a[RT];
            #pragma unroll
            for (int i = 0; i < RT; i += 4) {
                float4 av = *reinterpret_cast<const float4*>(&As[k][ty * RT + i]);
                a[i + 0] = av.x; a[i + 1] = av.y; a[i + 2] = av.z; a[i + 3] = av.w;
            }
            float4 bv = *reinterpret_cast<const float4*>(&Bs[k][tx * 4]);
            float b[4] = {bv.x, bv.y, bv.z, bv.w};
            #pragma unroll
            for (int i = 0; i < RT; i++)
                #pragma unroll
                for (int j = 0; j < 4; j++) acc[i][j] = fmaf(a[i], b[j], acc[i][j]);
        }
        __syncthreads();
    }
    float4 as4, ad4;
    if (FALPHA) {
        as4 = *reinterpret_cast<const float4*>(&a_s[col0 + tx * 4]);
        ad4 = *reinterpret_cast<const float4*>(&a_d[col0 + tx * 4]);
    }
    int HV = N >> 6, hd = col0 >> 6;
    #pragma unroll
    for (int i = 0; i < RT; i++) {
        int gr = row0 + ty * RT + i;
        if (gr < M) {
            if (WF32) {
                float4 v = make_float4(acc[i][0], acc[i][1], acc[i][2], acc[i][3]);
                *reinterpret_cast<float4*>(&C[(size_t)gr * N + col0 + tx * 4]) = v;
            }
            if (WBF16) {
                ushort4 u;
                u.x = f2bf(acc[i][0]); u.y = f2bf(acc[i][1]);
                u.z = f2bf(acc[i][2]); u.w = f2bf(acc[i][3]);
                *reinterpret_cast<ushort4*>(&Cb[(size_t)gr * N + col0 + tx * 4]) = u;
            }
            if (FALPHA) {
                float ps = acc[i][0] * as4.x + acc[i][1] * as4.y + acc[i][2] * as4.z + acc[i][3] * as4.w;
                float pd = acc[i][0] * ad4.x + acc[i][1] * ad4.y + acc[i][2] * ad4.z + acc[i][3] * ad4.w;
                #pragma unroll
                for (int off = 1; off <= 8; off <<= 1) { ps += __shfl_xor(ps, off); pd += __shfl_xor(pd, off); }
                if (tx == 0) { asrc[(size_t)gr * HV + hd] = ps; adst[(size_t)gr * HV + hd] = pd; }
            }
        }
    }
}

// ---------------- attention aggregation, layer 1 (ELL straight-line, bf16 gather) ----------------
// block = node; wave = head; lane: q = l&7 (8 channels x bf16x8), rep = l>>3.
// Each lane owns ELL slots rep*4..rep*4+3: one int4 col load, then 4 independent gathers.
__global__ __launch_bounds__(256) void k_agg1(const unsigned short* __restrict__ hb,
                                              const float* __restrict__ asrc, const float* __restrict__ adst,
                                              const int* __restrict__ rowptr, const int* __restrict__ ell,
                                              const int* __restrict__ col, const float* __restrict__ bias,
                                              float* __restrict__ out, int n) {
    int node = blockIdx.x;
    int t = threadIdx.x, hd = t >> 6, l = t & 63;
    int rep = l >> 3, q = l & 7;
    float adst_n = adst[node * 4 + hd];
    float p_self = __expf(leaky(asrc[node * 4 + hd] + adst_n));

    int4 cv = *reinterpret_cast<const int4*>(&ell[(size_t)node * ELLW + rep * 4]);
    int s0 = cv.x, s1 = cv.y, s2 = cv.z, s3 = cv.w;
    bool v0 = s0 >= 0, v1 = s1 >= 0, v2 = s2 >= 0, v3 = s3 >= 0;
    s0 = v0 ? s0 : 0; s1 = v1 ? s1 : 0; s2 = v2 ? s2 : 0; s3 = v3 ? s3 : 0;
    // all gathers independent -> issued back-to-back
    uint4 u0 = *reinterpret_cast<const uint4*>(&hb[(size_t)s0 * 256 + hd * 64 + q * 8]);
    uint4 u1 = *reinterpret_cast<const uint4*>(&hb[(size_t)s1 * 256 + hd * 64 + q * 8]);
    uint4 u2 = *reinterpret_cast<const uint4*>(&hb[(size_t)s2 * 256 + hd * 64 + q * 8]);
    uint4 u3 = *reinterpret_cast<const uint4*>(&hb[(size_t)s3 * 256 + hd * 64 + q * 8]);
    float e0 = asrc[s0 * 4 + hd], e1 = asrc[s1 * 4 + hd];
    float e2 = asrc[s2 * 4 + hd], e3 = asrc[s3 * 4 + hd];
    float p0 = v0 ? __expf(leaky(e0 + adst_n)) : 0.f;
    float p1 = v1 ? __expf(leaky(e1 + adst_n)) : 0.f;
    float p2 = v2 ? __expf(leaky(e2 + adst_n)) : 0.f;
    float p3 = v3 ? __expf(leaky(e3 + adst_n)) : 0.f;

    float acc[8] = {};
    float dsum = p0 + p1 + p2 + p3;
    if (rep == 0) {
        uint4 un = *reinterpret_cast<const uint4*>(&hb[(size_t)node * 256 + hd * 64 + q * 8]);
        float f[8];
        unpack2(un.x, f[0], f[1]); unpack2(un.y, f[2], f[3]);
        unpack2(un.z, f[4], f[5]); unpack2(un.w, f[6], f[7]);
        #pragma unroll
        for (int j = 0; j < 8; j++) acc[j] = p_self * f[j];
        dsum += p_self;
    }
    {
        float f[8];
        unpack2(u0.x, f[0], f[1]); unpack2(u0.y, f[2], f[3]);
        unpack2(u0.z, f[4], f[5]); unpack2(u0.w, f[6], f[7]);
        #pragma unroll
        for (int j = 0; j < 8; j++) acc[j] = fmaf(p0, f[j], acc[j]);
        unpack2(u1.x, f[0], f[1]); unpack2(u1.y, f[2], f[3]);
        unpack2(u1.z, f[4], f[5]); unpack2(u1.w, f[6], f[7]);
        #pragma unroll
        for (int j = 0; j < 8; j++) acc[j] = fmaf(p1, f[j], acc[j]);
        unpack2(u2.x, f[0], f[1]); unpack2(u2.y, f[2], f[3]);
        unpack2(u2.z, f[4], f[5]); unpack2(u2.w, f[6], f[7]);
        #pragma unroll
        for (int j = 0; j < 8; j++) acc[j] = fmaf(p2, f[j], acc[j]);
        unpack2(u3.x, f[0], f[1]); unpack2(u3.y, f[2], f[3]);
        unpack2(u3.z, f[4], f[5]); unpack2(u3.w, f[6], f[7]);
        #pragma unroll
        for (int j = 0; j < 8; j++) acc[j] = fmaf(p3, f[j], acc[j]);
    }
    // rare overflow tail via CSR (wave-uniform branch)
    int base = rowptr[node], deg = rowptr[node + 1] - base;
    if (deg > ELLW) {
        for (int c0 = ELLW; c0 < deg; c0 += 16) {
            int ia = c0 + rep, ib = ia + 8;
            bool va = ia < deg, vb = ib < deg;
            int sa = va ? col[base + ia] : 0;
            int sb = vb ? col[base + ib] : 0;
            uint4 ua = *reinterpret_cast<const uint4*>(&hb[(size_t)sa * 256 + hd * 64 + q * 8]);
            uint4 ub = *reinterpret_cast<const uint4*>(&hb[(size_t)sb * 256 + hd * 64 + q * 8]);
            float pa = va ? __expf(leaky(asrc[sa * 4 + hd] + adst_n)) : 0.f;
            float pb = vb ? __expf(leaky(asrc[sb * 4 + hd] + adst_n)) : 0.f;
            float f[8];
            unpack2(ua.x, f[0], f[1]); unpack2(ua.y, f[2], f[3]);
            unpack2(ua.z, f[4], f[5]); unpack2(ua.w, f[6], f[7]);
            #pragma unroll
            for (int j = 0; j < 8; j++) acc[j] = fmaf(pa, f[j], acc[j]);
            unpack2(ub.x, f[0], f[1]); unpack2(ub.y, f[2], f[3]);
            unpack2(ub.z, f[4], f[5]); unpack2(ub.w, f[6], f[7]);
            #pragma unroll
            for (int j = 0; j < 8; j++) acc[j] = fmaf(pb, f[j], acc[j]);
            dsum += pa + pb;
        }
    }
    // butterfly over rep bits (3,4,5)
    #pragma unroll
    for (int off = 8; off <= 32; off <<= 1) {
        #pragma unroll
        for (int j = 0; j < 8; j++) acc[j] += __shfl_xor(acc[j], off);
        dsum += __shfl_xor(dsum, off);
    }
    if (rep == 0) {
        float inv = 1.f / (dsum + 1e-16f);
        float r[8];
        #pragma unroll
        for (int j = 0; j < 8; j++) r[j] = fmaxf(acc[j] * inv + bias[hd * 64 + q * 8 + j], 0.f);
        float4 w0 = make_float4(r[0], r[1], r[2], r[3]);
        float4 w1 = make_float4(r[4], r[5], r[6], r[7]);
        *reinterpret_cast<float4*>(&out[(size_t)node * 256 + hd * 64 + q * 8]) = w0;
        *reinterpret_cast<float4*>(&out[(size_t)node * 256 + hd * 64 + q * 8 + 4]) = w1;
    }
}

// ---------------- attention aggregation, layer 2 (ELL straight-line) + fused FC ----------------
// wave = node (4 nodes/block); lane: q = l&7 (8 ch x bf16x8 = 64 ch), rep = l>>3.
__global__ __launch_bounds__(256) void k_agg2fc(const unsigned short* __restrict__ hb,
                                                const float* __restrict__ asrc, const float* __restrict__ adst,
                                                const int* __restrict__ rowptr, const int* __restrict__ ell,
                                                const int* __restrict__ col, const float* __restrict__ bias,
                                                const float* __restrict__ Wfc, const float* __restrict__ bfc,
                                                float* __restrict__ out, int n) {
    int node = blockIdx.x * 4 + (threadIdx.x >> 6);
    int l = threadIdx.x & 63;
    if (node >= n) return;
    int rep = l >> 3, q = l & 7;
    float adst_n = adst[node];
    float p_self = __expf(leaky(asrc[node] + adst_n));

    int4 cv = *reinterpret_cast<const int4*>(&ell[(size_t)node * ELLW + rep * 4]);
    int s0 = cv.x, s1 = cv.y, s2 = cv.z, s3 = cv.w;
    bool v0 = s0 >= 0, v1 = s1 >= 0, v2 = s2 >= 0, v3 = s3 >= 0;
    s0 = v0 ? s0 : 0; s1 = v1 ? s1 : 0; s2 = v2 ? s2 : 0; s3 = v3 ? s3 : 0;
    uint4 u0 = *reinterpret_cast<const uint4*>(&hb[(size_t)s0 * 64 + q * 8]);
    uint4 u1 = *reinterpret_cast<const uint4*>(&hb[(size_t)s1 * 64 + q * 8]);
    uint4 u2 = *reinterpret_cast<const uint4*>(&hb[(size_t)s2 * 64 + q * 8]);
    uint4 u3 = *reinterpret_cast<const uint4*>(&hb[(size_t)s3 * 64 + q * 8]);
    float e0 = asrc[s0], e1 = asrc[s1], e2 = asrc[s2], e3 = asrc[s3];
    float p0 = v0 ? __expf(leaky(e0 + adst_n)) : 0.f;
    float p1 = v1 ? __expf(leaky(e1 + adst_n)) : 0.f;
    float p2 = v2 ? __expf(leaky(e2 + adst_n)) : 0.f;
    float p3 = v3 ? __expf(leaky(e3 + adst_n)) : 0.f;

    float acc[8] = {};
    float dsum = p0 + p1 + p2 + p3;
    if (rep == 0) {
        uint4 un = *reinterpret_cast<const uint4*>(&hb[(size_t)node * 64 + q * 8]);
        float f[8];
        unpack2(un.x, f[0], f[1]); unpack2(un.y, f[2], f[3]);
        unpack2(un.z, f[4], f[5]); unpack2(un.w, f[6], f[7]);
        #pragma unroll
        for (int j = 0; j < 8; j++) acc[j] = p_self * f[j];
        dsum += p_self;
    }
    {
        float f[8];
        unpack2(u0.x, f[0], f[1]); unpack2(u0.y, f[2], f[3]);
        unpack2(u0.z, f[4], f[5]); unpack2(u0.w, f[6], f[7]);
        #pragma unroll
        for (int j = 0; j < 8; j++) acc[j] = fmaf(p0, f[j], acc[j]);
        unpack2(u1.x, f[0], f[1]); unpack2(u1.y, f[2], f[3]);
        unpack2(u1.z, f[4], f[5]); unpack2(u1.w, f[6], f[7]);
        #pragma unroll
        for (int j = 0; j < 8; j++) acc[j] = fmaf(p1, f[j], acc[j]);
        unpack2(u2.x, f[0], f[1]); unpack2(u2.y, f[2], f[3]);
        unpack2(u2.z, f[4], f[5]); unpack2(u2.w, f[6], f[7]);
        #pragma unroll
        for (int j = 0; j < 8; j++) acc[j] = fmaf(p2, f[j], acc[j]);
        unpack2(u3.x, f[0], f[1]); unpack2(u3.y, f[2], f[3]);
        unpack2(u3.z, f[4], f[5]); unpack2(u3.w, f[6], f[7]);
        #pragma unroll
        for (int j = 0; j < 8; j++) acc[j] = fmaf(p3, f[j], acc[j]);
    }
    int base = rowptr[node], deg = rowptr[node + 1] - base;
    if (deg > ELLW) {
        for (int c0 = ELLW; c0 < deg; c0 += 16) {
            int ia = c0 + rep, ib = ia + 8;
            bool va = ia < deg, vb = ib < deg;
            int sa = va ? col[base + ia] : 0;
            int sb = vb ? col[base + ib] : 0;
            uint4 ua = *reinterpret_cast<const uint4*>(&hb[(size_t)sa * 64 + q * 8]);
            uint4 ub = *reinterpret_cast<const uint4*>(&hb[(size_t)sb * 64 + q * 8]);
            float pa = va ? __expf(leaky(asrc[sa] + adst_n)) : 0.f;
            float pb = vb ? __expf(leaky(asrc[sb] + adst_n)) : 0.f;
            float f[8];
            unpack2(ua.x, f[0], f[1]); unpack2(ua.y, f[2], f[3]);
            unpack2(ua.z, f[4], f[5]); unpack2(ua.w, f[6], f[7]);
            #pragma unroll
            for (int j = 0; j < 8; j++) acc[j] = fmaf(pa, f[j], acc[j]);
            unpack2(ub.x, f[0], f[1]); unpack2(ub.y, f[2], f[3]);
            unpack2(ub.z, f[4], f[5]); unpack2(ub.w, f[6], f[7]);
            #pragma unroll
            for (int j = 0; j < 8; j++) acc[j] = fmaf(pb, f[j], acc[j]);
            dsum += pa + pb;
        }
    }
    #pragma unroll
    for (int off = 8; off <= 32; off <<= 1) {
        #pragma unroll
        for (int j = 0; j < 8; j++) acc[j] += __shfl_xor(acc[j], off);
        dsum += __shfl_xor(dsum, off);
    }
    float inv = 1.f / (dsum + 1e-16f);
    float r[8];
    #pragma unroll
    for (int j = 0; j < 8; j++) r[j] = fmaxf(acc[j] * inv + bias[q * 8 + j], 0.f);
    // fused FC over the 8 q-groups (lane bits 0..2)
    #pragma unroll
    for (int a = 0; a < 5; a++) {
        float part = 0.f;
        #pragma unroll
        for (int j = 0; j < 8; j++) part = fmaf(r[j], Wfc[(q * 8 + j) * 5 + a], part);
        #pragma unroll
        for (int off = 1; off <= 4; off <<= 1) part += __shfl_xor(part, off);
        if (l == 0) out[(size_t)node * 5 + a] = part + bfc[a];
    }
}

extern "C" void kernel_launch(void* const* d_in, const int* in_sizes, int n_in,
                              void* d_out, int out_size, void* d_ws, size_t ws_size,
                              hipStream_t stream) {
    const float* x   = (const float*)d_in[0];
    const int*   ei  = (const int*)d_in[1];
    const float* W1  = (const float*)d_in[2];
    const float* a1s = (const float*)d_in[3];
    const float* a1d = (const float*)d_in[4];
    const float* b1  = (const float*)d_in[5];
    const float* W2  = (const float*)d_in[6];
    const float* a2s = (const float*)d_in[7];
    const float* a2d = (const float*)d_in[8];
    const float* b2  = (const float*)d_in[9];
    const float* Wfc = (const float*)d_in[10];
    const float* bfc = (const float*)d_in[11];
    float* out = (float*)d_out;

    int n = in_sizes[0] / 128;
    int E = in_sizes[1] / 2;
    const int* srcn = ei;
    const int* dstn = ei + E;

    char* ws = (char*)d_ws;
    size_t off = 0;
    auto alloc = [&](size_t bytes) -> void* {
        void* p = ws + off;
        off += (bytes + 255) & ~(size_t)255;
        return p;
    };
    unsigned short* h1b = (unsigned short*)alloc((size_t)n * 256 * 2);
    float* out1   = (float*)alloc((size_t)n * 256 * 4);
    unsigned short* h2b = (unsigned short*)alloc((size_t)n * 64 * 2);
    float* asrc1  = (float*)alloc((size_t)n * 4 * 4);
    float* adst1  = (float*)alloc((size_t)n * 4 * 4);
    int*   rowptr = (int*)alloc((size_t)(n + 1) * 4);
    int*   wptr   = (int*)alloc((size_t)n * 4);
    int*   col    = (int*)alloc((size_t)E * 4);
    int*   ell    = (int*)alloc((size_t)n * ELLW * 4);
    int*   bsum   = (int*)alloc(64 * 4);
    int*   bscan  = (int*)alloc(64 * 4);
    float* asrc2 = asrc1;  // layer-1 versions dead before gemm2 writes these
    float* adst2 = adst1;

    int nb = (n + 1023) / 1024;

    // ---- CSR + ELL build (once; graph shared by both layers) ----
    hipMemsetAsync(wptr, 0, (size_t)n * 4, stream);
    hipMemsetAsync(ell, 0xFF, (size_t)n * ELLW * 4, stream);
    k_count<<<(E + 255) / 256, 256, 0, stream>>>(dstn, E, wptr);
    k_scanA<<<nb, 256, 0, stream>>>(wptr, rowptr, bsum, n);
    k_scanB<<<1, 64, 0, stream>>>(bsum, bscan, nb);
    k_scanC<<<nb, 256, 0, stream>>>(rowptr, bscan, n);
    k_copy<<<(n + 255) / 256, 256, 0, stream>>>(rowptr, wptr, n);
    k_scatter<<<(E + 255) / 256, 256, 0, stream>>>(srcn, dstn, E, rowptr, wptr, col, ell);

    // ---- layer 1: GEMM (bf16 out + fused alpha), then aggregation ----
    k_gemm<128, false, true, true><<<dim3((n + 127) / 128, 4), 256, 0, stream>>>(
        x, W1, nullptr, h1b, a1s, a1d, asrc1, adst1, n, 256, 128);
    k_agg1<<<n, 256, 0, stream>>>(h1b, asrc1, adst1, rowptr, ell, col, b1, out1, n);
    // ---- layer 2: GEMM (bf16 out + fused alpha), aggregation + FC fused ----
    k_gemm<64, false, true, true><<<dim3((n + 63) / 64, 1), 256, 0, stream>>>(
        out1, W2, nullptr, h2b, a2s, a2d, asrc2, adst2, n, 64, 256);
    k_agg2fc<<<(n + 3) / 4, 256, 0, stream>>>(h2b, asrc2, adst2, rowptr, ell, col, b2, Wfc, bfc, out, n);
}